// Round 15
// baseline (308.072 us; speedup 1.0000x reference)
//
#include <hip/hip_runtime.h>
#include <hip/hip_bf16.h>
#include <math.h>

#define N_NODES 50000

typedef short short8 __attribute__((ext_vector_type(8)));
typedef float f32x4 __attribute__((ext_vector_type(4)));

// RNE split of f32 into bf16 hi + bf16 lo (a ~= hi + lo, rel err ~2^-18)
static __device__ __forceinline__ void split2(float x, unsigned short& hi, unsigned short& lo) {
    unsigned u = __builtin_bit_cast(unsigned, x);
    unsigned r = u + 0x7FFF + ((u >> 16) & 1);
    hi = (unsigned short)(r >> 16);
    float hf = __builtin_bit_cast(float, (unsigned)hi << 16);
    float res = x - hf;
    unsigned v = __builtin_bit_cast(unsigned, res);
    unsigned r2 = v + 0x7FFF + ((v >> 16) & 1);
    lo = (unsigned short)(r2 >> 16);
}

// ---------------- degree (int histogram) ----------------

__global__ void deg_kernel(const int* __restrict__ dst, int* __restrict__ deg, int E) {
    int e = blockIdx.x * blockDim.x + threadIdx.x;
    if (e < E) atomicAdd(&deg[dst[e]], 1);
}

// ---------------- multi-block exclusive scan ----------------

__global__ void scan_p1(const int* __restrict__ deg, int* __restrict__ bsum, int n) {
    int t = threadIdx.x;                    // 256 threads
    int base = blockIdx.x * 1024 + t * 4;
    int4 v = make_int4(0, 0, 0, 0);
    if (base + 3 < n) v = *(const int4*)(deg + base);
    else {
        if (base + 0 < n) v.x = deg[base + 0];
        if (base + 1 < n) v.y = deg[base + 1];
        if (base + 2 < n) v.z = deg[base + 2];
    }
    int s = v.x + v.y + v.z + v.w;
    #pragma unroll
    for (int off = 32; off > 0; off >>= 1) s += __shfl_xor(s, off);
    __shared__ int wpart[4];
    if ((t & 63) == 0) wpart[t >> 6] = s;
    __syncthreads();
    if (t == 0) bsum[blockIdx.x] = wpart[0] + wpart[1] + wpart[2] + wpart[3];
}

__global__ void scan_p2(int* __restrict__ bsum, int nb, int* __restrict__ rowptr, int n) {
    int t = threadIdx.x;                    // 64 threads, nb <= 64
    int v = (t < nb) ? bsum[t] : 0;
    int sc = v;
    #pragma unroll
    for (int off = 1; off < 64; off <<= 1) {
        int u = __shfl_up(sc, off);
        if (t >= off) sc += u;
    }
    if (t < nb) bsum[t] = sc - v;           // exclusive block offsets
    if (t == 63) rowptr[n] = sc;            // grand total
}

// scan_p3 also computes inv_sqrt(deg) (folded kernel)
__global__ void scan_p3(const int* __restrict__ deg, const int* __restrict__ bsum,
                        int* __restrict__ rowptr, int* __restrict__ cursor,
                        float* __restrict__ inv, int n) {
    int t = threadIdx.x;                    // 256 threads
    int base = blockIdx.x * 1024 + t * 4;
    int4 v = make_int4(0, 0, 0, 0);
    if (base + 3 < n) v = *(const int4*)(deg + base);
    else {
        if (base + 0 < n) v.x = deg[base + 0];
        if (base + 1 < n) v.y = deg[base + 1];
        if (base + 2 < n) v.z = deg[base + 2];
    }
    int s = v.x + v.y + v.z + v.w;
    int lane = t & 63;
    int sc = s;
    #pragma unroll
    for (int off = 1; off < 64; off <<= 1) {
        int u = __shfl_up(sc, off);
        if (lane >= off) sc += u;
    }
    __shared__ int wpart[4], woff[4];
    if (lane == 63) wpart[t >> 6] = sc;
    __syncthreads();
    if (t == 0) { int a = 0; for (int i = 0; i < 4; ++i) { woff[i] = a; a += wpart[i]; } }
    __syncthreads();
    int run = bsum[blockIdx.x] + woff[t >> 6] + (sc - s);
    if (base + 0 < n) { rowptr[base + 0] = run; cursor[base + 0] = run; run += v.x; inv[base + 0] = rsqrtf(fmaxf((float)v.x, 1.0f)); }
    if (base + 1 < n) { rowptr[base + 1] = run; cursor[base + 1] = run; run += v.y; inv[base + 1] = rsqrtf(fmaxf((float)v.y, 1.0f)); }
    if (base + 2 < n) { rowptr[base + 2] = run; cursor[base + 2] = run; run += v.z; inv[base + 2] = rsqrtf(fmaxf((float)v.z, 1.0f)); }
    if (base + 3 < n) { rowptr[base + 3] = run; cursor[base + 3] = run; run += v.w; inv[base + 3] = rsqrtf(fmaxf((float)v.w, 1.0f)); }
}

// ---------------- bucket edges by dst (counting sort fill, packed 8B) ----------------

__global__ void fill_kernel(const int* __restrict__ src, const int* __restrict__ dst,
                            const float* __restrict__ inv, int* __restrict__ cursor,
                            int2* __restrict__ edges, int E) {
    int e = blockIdx.x * blockDim.x + threadIdx.x;
    if (e >= E) return;
    int s = src[e];
    int d = dst[e];
    int pos = atomicAdd(&cursor[d], 1);
    float nv = inv[s] * inv[d];
    edges[pos] = make_int2(s, __builtin_bit_cast(int, nv));
}

// ---------------- gather aggregation pass: one wave per node, 128 cols/pass ----------------
// edges packed as (src:int, norm:f32) int2 pairs, read sequentially per bucket.

__global__ void gather_agg_pass(const float* __restrict__ x, int coff, int ss,
                                const int* __restrict__ rowptr, const int2* __restrict__ edges,
                                unsigned short* __restrict__ agg_hi,
                                unsigned short* __restrict__ agg_lo, int as) {
    int node = blockIdx.x * 4 + (threadIdx.x >> 6);
    if (node >= N_NODES) return;
    int lane = threadIdx.x & 63;
    int beg = rowptr[node];
    int end = rowptr[node + 1];
    const float* xb = x + coff + (size_t)lane * 2;

    float2 acc = {0.0f, 0.0f};
    int p = beg;
    for (; p + 4 <= end; p += 4) {
        int2 e0 = edges[p], e1 = edges[p + 1], e2 = edges[p + 2], e3 = edges[p + 3];
        float n0 = __builtin_bit_cast(float, e0.y);
        float n1 = __builtin_bit_cast(float, e1.y);
        float n2 = __builtin_bit_cast(float, e2.y);
        float n3 = __builtin_bit_cast(float, e3.y);
        float2 v0 = *(const float2*)(xb + (size_t)e0.x * ss);
        float2 v1 = *(const float2*)(xb + (size_t)e1.x * ss);
        float2 v2 = *(const float2*)(xb + (size_t)e2.x * ss);
        float2 v3 = *(const float2*)(xb + (size_t)e3.x * ss);
        acc.x = fmaf(v0.x, n0, acc.x); acc.y = fmaf(v0.y, n0, acc.y);
        acc.x = fmaf(v1.x, n1, acc.x); acc.y = fmaf(v1.y, n1, acc.y);
        acc.x = fmaf(v2.x, n2, acc.x); acc.y = fmaf(v2.y, n2, acc.y);
        acc.x = fmaf(v3.x, n3, acc.x); acc.y = fmaf(v3.y, n3, acc.y);
    }
    for (; p < end; ++p) {
        int2 e0 = edges[p];
        float n0 = __builtin_bit_cast(float, e0.y);
        float2 v0 = *(const float2*)(xb + (size_t)e0.x * ss);
        acc.x = fmaf(v0.x, n0, acc.x);
        acc.y = fmaf(v0.y, n0, acc.y);
    }

    unsigned short h0, l0, h1, l1;
    split2(acc.x, h0, l0);
    split2(acc.y, h1, l1);
    unsigned hp = (unsigned)h0 | ((unsigned)h1 << 16);
    unsigned lp = (unsigned)l0 | ((unsigned)l1 << 16);
    size_t o = (size_t)node * as + coff + (size_t)lane * 2;
    *(unsigned*)(agg_hi + o) = hp;
    *(unsigned*)(agg_lo + o) = lp;
}

// ---------------- W split + transpose (W1, W2, Wd in one launch) ----------------
// W[K][256] -> [256][K] bf16 hi/lo; Wd[256][40] -> [48][256] (rows 40-47 zero).

__global__ void split_w_all(const float* __restrict__ W1, const float* __restrict__ W2,
                            const float* __restrict__ Wd,
                            unsigned short* __restrict__ w1hi, unsigned short* __restrict__ w1lo,
                            unsigned short* __restrict__ w2hi, unsigned short* __restrict__ w2lo,
                            unsigned short* __restrict__ wdhi, unsigned short* __restrict__ wdlo) {
    int i = blockIdx.x * 256 + threadIdx.x;
    if (i < 128 * 256) {
        int k = i >> 8;
        int n = i & 255;
        unsigned short h, l;
        split2(W1[i], h, l);
        w1hi[(size_t)n * 128 + k] = h;
        w1lo[(size_t)n * 128 + k] = l;
    } else if (i < 128 * 256 + 256 * 256) {
        int j = i - 128 * 256;
        int k = j >> 8;
        int n = j & 255;
        unsigned short h, l;
        split2(W2[j], h, l);
        w2hi[(size_t)n * 256 + k] = h;
        w2lo[(size_t)n * 256 + k] = l;
    } else {
        int j = i - 128 * 256 - 256 * 256;   // 0 .. 48*256-1
        int c = j >> 8;                       // 0..47
        int k = j & 255;
        float val = (c < 40) ? Wd[(size_t)k * 40 + c] : 0.0f;
        unsigned short h, l;
        split2(val, h, l);
        wdhi[(size_t)c * 256 + k] = h;
        wdlo[(size_t)c * 256 + k] = l;
    }
}

// ---------------- MFMA GEMM (split bf16, swapped operands), 128-row tile ----------------
// out = relu(A[M,K] @ W[K,256] + b); f32 out (SPLIT_OUT=0) or split-bf16 hi/lo (=1).

template<int K, bool SPLIT_OUT>
__global__ __launch_bounds__(256, 2) void gemm_mfma_kernel(
    const unsigned short* __restrict__ Ahi, const unsigned short* __restrict__ Alo,
    const unsigned short* __restrict__ Bhi, const unsigned short* __restrict__ Blo,
    const float* __restrict__ bias, float* __restrict__ out,
    unsigned short* __restrict__ outHi, unsigned short* __restrict__ outLo, int M)
{
    constexpr int ROWS = 128;
    __shared__ unsigned short AsH[2][ROWS][40];
    __shared__ unsigned short AsL[2][ROWS][40];

    int tid = threadIdx.x;
    int lane = tid & 63;
    int wave = tid >> 6;
    int row0 = blockIdx.x * ROWS;
    int col0 = wave * 64;
    int lr = lane & 15;
    int lhi = lane >> 4;
    int koff0 = lhi * 8;

    // staging: threads 0-127 stage hi, 128-255 stage lo; 4 short8 slots each/chunk
    const unsigned short* Asrc = (tid < 128) ? Ahi : Alo;
    int s = tid & 127;
    int srow0 = s >> 2;                     // 0..31 (slot j adds j*32)
    int skg = (s & 3) << 3;                 // 0,8,16,24

    f32x4 acc[4][8];
    #pragma unroll
    for (int i = 0; i < 4; ++i)
        #pragma unroll
        for (int j = 0; j < 8; ++j) acc[i][j] = (f32x4){0.f, 0.f, 0.f, 0.f};

    short8 rr[4];
    // prologue: stage chunk 0
    #pragma unroll
    for (int j = 0; j < 4; ++j)
        rr[j] = *(const short8*)(Asrc + (size_t)(row0 + j * 32 + srow0) * K + skg);
    #pragma unroll
    for (int j = 0; j < 4; ++j) {
        if (tid < 128) *(short8*)&AsH[0][j * 32 + srow0][skg] = rr[j];
        else           *(short8*)&AsL[0][j * 32 + srow0][skg] = rr[j];
    }
    __syncthreads();

    constexpr int NT = K / 32;
    #pragma unroll 1
    for (int t = 0; t < NT; ++t) {
        int cur = t & 1;
        int ko = t * 32 + koff0;

        // B fragments (L2-hot) — issued FIRST
        short8 bh[4], bl[4];
        #pragma unroll
        for (int cf = 0; cf < 4; ++cf) {
            size_t boff = (size_t)(col0 + cf * 16 + lr) * K + ko;
            bh[cf] = *(const short8*)(Bhi + boff);
            bl[cf] = *(const short8*)(Blo + boff);
        }

        // A prefetch for next chunk (HBM) — stays in flight during MFMA
        if (t + 1 < NT) {
            int kk = (t + 1) * 32;
            #pragma unroll
            for (int j = 0; j < 4; ++j)
                rr[j] = *(const short8*)(Asrc + (size_t)(row0 + j * 32 + srow0) * K + kk + skg);
        }

        // compute in two rf-halves to bound register pressure
        #pragma unroll
        for (int half = 0; half < 2; ++half) {
            short8 ah[4], al[4];
            #pragma unroll
            for (int rf = 0; rf < 4; ++rf) {
                int row = (half * 4 + rf) * 16 + lr;
                ah[rf] = *(const short8*)&AsH[cur][row][koff0];
                al[rf] = *(const short8*)&AsL[cur][row][koff0];
            }
            #pragma unroll
            for (int cf = 0; cf < 4; ++cf)
                #pragma unroll
                for (int rf = 0; rf < 4; ++rf) {
                    int rfx = half * 4 + rf;
                    acc[cf][rfx] = __builtin_amdgcn_mfma_f32_16x16x32_bf16(bh[cf], ah[rf], acc[cf][rfx], 0, 0, 0);
                    acc[cf][rfx] = __builtin_amdgcn_mfma_f32_16x16x32_bf16(bl[cf], ah[rf], acc[cf][rfx], 0, 0, 0);
                    acc[cf][rfx] = __builtin_amdgcn_mfma_f32_16x16x32_bf16(bh[cf], al[rf], acc[cf][rfx], 0, 0, 0);
                }
        }

        if (t + 1 < NT) {
            #pragma unroll
            for (int j = 0; j < 4; ++j) {
                if (tid < 128) *(short8*)&AsH[cur ^ 1][j * 32 + srow0][skg] = rr[j];
                else           *(short8*)&AsL[cur ^ 1][j * 32 + srow0][skg] = rr[j];
            }
        }
        __syncthreads();
    }

    // epilogue: bias + relu; f32 float4 stores or split-bf16 ushort4 stores
    #pragma unroll
    for (int cf = 0; cf < 4; ++cf) {
        int c = col0 + cf * 16 + lhi * 4;
        float4 bv = *(const float4*)(bias + c);
        #pragma unroll
        for (int rfx = 0; rfx < 8; ++rfx) {
            int r = row0 + rfx * 16 + lr;
            if (r < M) {
                float v0 = fmaxf(acc[cf][rfx][0] + bv.x, 0.f);
                float v1 = fmaxf(acc[cf][rfx][1] + bv.y, 0.f);
                float v2 = fmaxf(acc[cf][rfx][2] + bv.z, 0.f);
                float v3 = fmaxf(acc[cf][rfx][3] + bv.w, 0.f);
                if (!SPLIT_OUT) {
                    float4 v = make_float4(v0, v1, v2, v3);
                    *(float4*)(out + (size_t)r * 256 + c) = v;
                } else {
                    ushort4 hv, lv;
                    split2(v0, hv.x, lv.x);
                    split2(v1, hv.y, lv.y);
                    split2(v2, hv.z, lv.z);
                    split2(v3, hv.w, lv.w);
                    *(ushort4*)(outHi + (size_t)r * 256 + c) = hv;
                    *(ushort4*)(outLo + (size_t)r * 256 + c) = lv;
                }
            }
        }
    }
}

// ---------------- dense head via MFMA + fused softmax (no LDS, no barriers) ----------------
// out[M,40] = softmax(h2[M,256] @ Wd[256,40] + bd). h2 as split-bf16 hi/lo [M][256];
// Wd pre-split/transposed [48][256] (rows 40-47 zero). Block = 4 waves x 16 rows.
// Wave: 16 rows x 48 cols, acc[3] frags. D = mfma(Wd_frag, H_frag): lane holds
// row r = row0+(lane&15), cols c = cf*16+(lane>>4)*4+reg. Softmax per row =
// local max/sum + shfl_xor(16,32) across the 4-lane row group. float4 stores.

__global__ __launch_bounds__(256) void dense_mfma_kernel(
    const unsigned short* __restrict__ Hhi, const unsigned short* __restrict__ Hlo,
    const unsigned short* __restrict__ Dhi, const unsigned short* __restrict__ Dlo,
    const float* __restrict__ bd, float* __restrict__ out, int M)
{
    int tid = threadIdx.x;
    int lane = tid & 63;
    int wave = tid >> 6;
    int row0 = blockIdx.x * 64 + wave * 16;
    int lr = lane & 15;
    int lhi = lane >> 4;
    int koff0 = lhi * 8;

    f32x4 acc[3];
    #pragma unroll
    for (int i = 0; i < 3; ++i) acc[i] = (f32x4){0.f, 0.f, 0.f, 0.f};

    size_t abase = (size_t)(row0 + lr) * 256 + koff0;
    short8 ah = *(const short8*)(Hhi + abase);
    short8 al = *(const short8*)(Hlo + abase);

    #pragma unroll
    for (int t = 0; t < 8; ++t) {
        short8 ah2, al2;
        if (t + 1 < 8) {                     // prefetch next h-chunk
            ah2 = *(const short8*)(Hhi + abase + (t + 1) * 32);
            al2 = *(const short8*)(Hlo + abase + (t + 1) * 32);
        }
        int ko = t * 32 + koff0;
        #pragma unroll
        for (int cf = 0; cf < 3; ++cf) {
            size_t boff = (size_t)(cf * 16 + lr) * 256 + ko;
            short8 bh = *(const short8*)(Dhi + boff);
            short8 bl = *(const short8*)(Dlo + boff);
            acc[cf] = __builtin_amdgcn_mfma_f32_16x16x32_bf16(bh, ah, acc[cf], 0, 0, 0);
            acc[cf] = __builtin_amdgcn_mfma_f32_16x16x32_bf16(bl, ah, acc[cf], 0, 0, 0);
            acc[cf] = __builtin_amdgcn_mfma_f32_16x16x32_bf16(bh, al, acc[cf], 0, 0, 0);
        }
        if (t + 1 < 8) { ah = ah2; al = al2; }
    }

    // logits + bias; cols c = cf*16 + lhi*4 + reg; cf==2 valid only for lhi<2
    bool v2 = (lhi < 2);
    float4 b0 = *(const float4*)(bd + lhi * 4);
    float4 b1 = *(const float4*)(bd + 16 + lhi * 4);
    float4 b2 = v2 ? *(const float4*)(bd + 32 + lhi * 4) : make_float4(0.f, 0.f, 0.f, 0.f);

    float l0[4], l1[4], l2[4];
    const float* pb0 = (const float*)&b0;
    const float* pb1 = (const float*)&b1;
    const float* pb2 = (const float*)&b2;
    #pragma unroll
    for (int j = 0; j < 4; ++j) {
        l0[j] = acc[0][j] + pb0[j];
        l1[j] = acc[1][j] + pb1[j];
        l2[j] = v2 ? (acc[2][j] + pb2[j]) : -INFINITY;
    }

    float m = l0[0];
    #pragma unroll
    for (int j = 0; j < 4; ++j) { m = fmaxf(m, l0[j]); m = fmaxf(m, l1[j]); m = fmaxf(m, l2[j]); }
    m = fmaxf(m, __shfl_xor(m, 16));
    m = fmaxf(m, __shfl_xor(m, 32));

    float e0[4], e1[4], e2[4];
    float ssum = 0.f;
    #pragma unroll
    for (int j = 0; j < 4; ++j) {
        e0[j] = expf(l0[j] - m); ssum += e0[j];
        e1[j] = expf(l1[j] - m); ssum += e1[j];
        e2[j] = v2 ? expf(l2[j] - m) : 0.f; ssum += e2[j];
    }
    ssum += __shfl_xor(ssum, 16);
    ssum += __shfl_xor(ssum, 32);

    int r = row0 + lr;
    if (r < M) {
        float is = 1.0f / ssum;
        float* orow = out + (size_t)r * 40;
        *(float4*)(orow + lhi * 4)      = make_float4(e0[0] * is, e0[1] * is, e0[2] * is, e0[3] * is);
        *(float4*)(orow + 16 + lhi * 4) = make_float4(e1[0] * is, e1[1] * is, e1[2] * is, e1[3] * is);
        if (v2)
            *(float4*)(orow + 32 + lhi * 4) = make_float4(e2[0] * is, e2[1] * is, e2[2] * is, e2[3] * is);
    }
}

// ---------------- launch ----------------

extern "C" void kernel_launch(void* const* d_in, const int* in_sizes, int n_in,
                              void* d_out, int out_size, void* d_ws, size_t ws_size,
                              hipStream_t stream) {
    const float* x  = (const float*)d_in[0];
    const int*   ei = (const int*)d_in[1];
    const float* W1 = (const float*)d_in[2];
    const float* b1 = (const float*)d_in[3];
    const float* W2 = (const float*)d_in[4];
    const float* b2 = (const float*)d_in[5];
    const float* Wd = (const float*)d_in[6];
    const float* bd = (const float*)d_in[7];
    float* out = (float*)d_out;

    const int N = N_NODES;
    const int E = in_sizes[1] / 2;
    const int* src = ei;
    const int* dst = ei + E;

    const int MP = 50048;   // M padded to multiple of 128 for MFMA tiles (128*391)

    // workspace layout (bytes, 1KB-aligned). ~110 MB.
    char* ws = (char*)d_ws;
    size_t off = 0;
    auto alloc = [&](size_t bytes) { char* p = ws + off; off += (bytes + 1023) & ~(size_t)1023; return p; };
    int*   deg    = (int*)alloc((size_t)N * 4);
    float* inv    = (float*)alloc((size_t)N * 4);
    int*   rowptr = (int*)alloc((size_t)(N + 1) * 4);
    int*   cursor = (int*)alloc((size_t)N * 4);
    int*   bsum   = (int*)alloc((size_t)64 * 4);
    int2*  edges  = (int2*)alloc((size_t)E * 8);
    float* h1     = (float*)alloc((size_t)MP * 256 * 4);                   // conv1 out f32; reused as h2 split
    unsigned short* aggU = (unsigned short*)alloc((size_t)MP * 256 * 2 * 2); // union region
    unsigned short* w1hi = (unsigned short*)alloc((size_t)128 * 256 * 2);
    unsigned short* w1lo = (unsigned short*)alloc((size_t)128 * 256 * 2);
    unsigned short* w2hi = (unsigned short*)alloc((size_t)256 * 256 * 2);
    unsigned short* w2lo = (unsigned short*)alloc((size_t)256 * 256 * 2);
    unsigned short* wdhi = (unsigned short*)alloc((size_t)48 * 256 * 2);
    unsigned short* wdlo = (unsigned short*)alloc((size_t)48 * 256 * 2);

    // union aliases: agg1 (K=128) uses first half; agg2 (K=256) uses whole region
    unsigned short* agg1_hi = aggU;
    unsigned short* agg1_lo = aggU + (size_t)MP * 128;
    unsigned short* agg2_hi = aggU;
    unsigned short* agg2_lo = aggU + (size_t)MP * 256;
    // h2 split-bf16 aliases h1 (h1 dead once agg2 is built)
    unsigned short* h2hi = (unsigned short*)h1;
    unsigned short* h2lo = h2hi + (size_t)MP * 256;

    hipMemsetAsync(deg, 0, (size_t)N * 4, stream);

    const int nb = (N + 1023) / 1024;   // 49 scan blocks

    // degree -> scan (rowptr+cursor+inv) -> bucketed packed edges
    deg_kernel<<<(E + 255) / 256, 256, 0, stream>>>(dst, deg, E);
    scan_p1<<<nb, 256, 0, stream>>>(deg, bsum, N);
    scan_p2<<<1, 64, 0, stream>>>(bsum, nb, rowptr, N);
    scan_p3<<<nb, 256, 0, stream>>>(deg, bsum, rowptr, cursor, inv, N);
    fill_kernel<<<(E + 255) / 256, 256, 0, stream>>>(src, dst, inv, cursor, edges, E);

    // pre-split weights (W1, W2, Wd transposed), one launch
    split_w_all<<<(128 * 256 + 256 * 256 + 48 * 256) / 256, 256, 0, stream>>>(
        W1, W2, Wd, w1hi, w1lo, w2hi, w2lo, wdhi, wdlo);

    const int gblocks = (N + 3) / 4;

    // conv1: gather into agg1 (split bf16), then h1 = relu(agg1 @ W1 + b1) via MFMA (f32 out)
    gather_agg_pass<<<gblocks, 256, 0, stream>>>(x, 0, 128, rowptr, edges, agg1_hi, agg1_lo, 128);
    gemm_mfma_kernel<128, false><<<MP / 128, 256, 0, stream>>>(
        agg1_hi, agg1_lo, w1hi, w1lo, b1, h1, nullptr, nullptr, N);

    // conv2: gather h1 into agg2 (two 128-col passes), then h2 = relu(...) as split bf16
    gather_agg_pass<<<gblocks, 256, 0, stream>>>(h1, 0,   256, rowptr, edges, agg2_hi, agg2_lo, 256);
    gather_agg_pass<<<gblocks, 256, 0, stream>>>(h1, 128, 256, rowptr, edges, agg2_hi, agg2_lo, 256);
    gemm_mfma_kernel<256, true><<<MP / 128, 256, 0, stream>>>(
        agg2_hi, agg2_lo, w2hi, w2lo, b2, nullptr, h2hi, h2lo, N);

    // dense + softmax via MFMA (no LDS)
    dense_mfma_kernel<<<MP / 64, 256, 0, stream>>>(h2hi, h2lo, wdhi, wdlo, bd, out, N);
}

// Round 16
// 297.638 us; speedup vs baseline: 1.0351x; 1.0351x over previous
//
#include <hip/hip_runtime.h>
#include <hip/hip_bf16.h>
#include <math.h>

#define N_NODES 50000

typedef short short8 __attribute__((ext_vector_type(8)));
typedef float f32x4 __attribute__((ext_vector_type(4)));

// RNE split of f32 into bf16 hi + bf16 lo (a ~= hi + lo, rel err ~2^-18)
static __device__ __forceinline__ void split2(float x, unsigned short& hi, unsigned short& lo) {
    unsigned u = __builtin_bit_cast(unsigned, x);
    unsigned r = u + 0x7FFF + ((u >> 16) & 1);
    hi = (unsigned short)(r >> 16);
    float hf = __builtin_bit_cast(float, (unsigned)hi << 16);
    float res = x - hf;
    unsigned v = __builtin_bit_cast(unsigned, res);
    unsigned r2 = v + 0x7FFF + ((v >> 16) & 1);
    lo = (unsigned short)(r2 >> 16);
}

// ---------------- degree (int histogram) ----------------

__global__ void deg_kernel(const int* __restrict__ dst, int* __restrict__ deg, int E) {
    int e = blockIdx.x * blockDim.x + threadIdx.x;
    if (e < E) atomicAdd(&deg[dst[e]], 1);
}

// ---------------- multi-block exclusive scan ----------------

__global__ void scan_p1(const int* __restrict__ deg, int* __restrict__ bsum, int n) {
    int t = threadIdx.x;                    // 256 threads
    int base = blockIdx.x * 1024 + t * 4;
    int4 v = make_int4(0, 0, 0, 0);
    if (base + 3 < n) v = *(const int4*)(deg + base);
    else {
        if (base + 0 < n) v.x = deg[base + 0];
        if (base + 1 < n) v.y = deg[base + 1];
        if (base + 2 < n) v.z = deg[base + 2];
    }
    int s = v.x + v.y + v.z + v.w;
    #pragma unroll
    for (int off = 32; off > 0; off >>= 1) s += __shfl_xor(s, off);
    __shared__ int wpart[4];
    if ((t & 63) == 0) wpart[t >> 6] = s;
    __syncthreads();
    if (t == 0) bsum[blockIdx.x] = wpart[0] + wpart[1] + wpart[2] + wpart[3];
}

__global__ void scan_p2(int* __restrict__ bsum, int nb, int* __restrict__ rowptr, int n) {
    int t = threadIdx.x;                    // 64 threads, nb <= 64
    int v = (t < nb) ? bsum[t] : 0;
    int sc = v;
    #pragma unroll
    for (int off = 1; off < 64; off <<= 1) {
        int u = __shfl_up(sc, off);
        if (t >= off) sc += u;
    }
    if (t < nb) bsum[t] = sc - v;           // exclusive block offsets
    if (t == 63) rowptr[n] = sc;            // grand total
}

// scan_p3 also computes inv_sqrt(deg) (folded kernel)
__global__ void scan_p3(const int* __restrict__ deg, const int* __restrict__ bsum,
                        int* __restrict__ rowptr, int* __restrict__ cursor,
                        float* __restrict__ inv, int n) {
    int t = threadIdx.x;                    // 256 threads
    int base = blockIdx.x * 1024 + t * 4;
    int4 v = make_int4(0, 0, 0, 0);
    if (base + 3 < n) v = *(const int4*)(deg + base);
    else {
        if (base + 0 < n) v.x = deg[base + 0];
        if (base + 1 < n) v.y = deg[base + 1];
        if (base + 2 < n) v.z = deg[base + 2];
    }
    int s = v.x + v.y + v.z + v.w;
    int lane = t & 63;
    int sc = s;
    #pragma unroll
    for (int off = 1; off < 64; off <<= 1) {
        int u = __shfl_up(sc, off);
        if (lane >= off) sc += u;
    }
    __shared__ int wpart[4], woff[4];
    if (lane == 63) wpart[t >> 6] = sc;
    __syncthreads();
    if (t == 0) { int a = 0; for (int i = 0; i < 4; ++i) { woff[i] = a; a += wpart[i]; } }
    __syncthreads();
    int run = bsum[blockIdx.x] + woff[t >> 6] + (sc - s);
    if (base + 0 < n) { rowptr[base + 0] = run; cursor[base + 0] = run; run += v.x; inv[base + 0] = rsqrtf(fmaxf((float)v.x, 1.0f)); }
    if (base + 1 < n) { rowptr[base + 1] = run; cursor[base + 1] = run; run += v.y; inv[base + 1] = rsqrtf(fmaxf((float)v.y, 1.0f)); }
    if (base + 2 < n) { rowptr[base + 2] = run; cursor[base + 2] = run; run += v.z; inv[base + 2] = rsqrtf(fmaxf((float)v.z, 1.0f)); }
    if (base + 3 < n) { rowptr[base + 3] = run; cursor[base + 3] = run; run += v.w; inv[base + 3] = rsqrtf(fmaxf((float)v.w, 1.0f)); }
}

// ---------------- bucket edges by dst (counting sort fill, packed 8B) ----------------

__global__ void fill_kernel(const int* __restrict__ src, const int* __restrict__ dst,
                            const float* __restrict__ inv, int* __restrict__ cursor,
                            int2* __restrict__ edges, int E) {
    int e = blockIdx.x * blockDim.x + threadIdx.x;
    if (e >= E) return;
    int s = src[e];
    int d = dst[e];
    int pos = atomicAdd(&cursor[d], 1);
    float nv = inv[s] * inv[d];
    edges[pos] = make_int2(s, __builtin_bit_cast(int, nv));
}

// ---------------- gather aggregation pass: one wave per node, 128 cols/pass ----------------
// edges packed as (src:int, norm:f32) int2 pairs, read sequentially per bucket.

__global__ void gather_agg_pass(const float* __restrict__ x, int coff, int ss,
                                const int* __restrict__ rowptr, const int2* __restrict__ edges,
                                unsigned short* __restrict__ agg_hi,
                                unsigned short* __restrict__ agg_lo, int as) {
    int node = blockIdx.x * 4 + (threadIdx.x >> 6);
    if (node >= N_NODES) return;
    int lane = threadIdx.x & 63;
    int beg = rowptr[node];
    int end = rowptr[node + 1];
    const float* xb = x + coff + (size_t)lane * 2;

    float2 acc = {0.0f, 0.0f};
    int p = beg;
    for (; p + 4 <= end; p += 4) {
        int2 e0 = edges[p], e1 = edges[p + 1], e2 = edges[p + 2], e3 = edges[p + 3];
        float n0 = __builtin_bit_cast(float, e0.y);
        float n1 = __builtin_bit_cast(float, e1.y);
        float n2 = __builtin_bit_cast(float, e2.y);
        float n3 = __builtin_bit_cast(float, e3.y);
        float2 v0 = *(const float2*)(xb + (size_t)e0.x * ss);
        float2 v1 = *(const float2*)(xb + (size_t)e1.x * ss);
        float2 v2 = *(const float2*)(xb + (size_t)e2.x * ss);
        float2 v3 = *(const float2*)(xb + (size_t)e3.x * ss);
        acc.x = fmaf(v0.x, n0, acc.x); acc.y = fmaf(v0.y, n0, acc.y);
        acc.x = fmaf(v1.x, n1, acc.x); acc.y = fmaf(v1.y, n1, acc.y);
        acc.x = fmaf(v2.x, n2, acc.x); acc.y = fmaf(v2.y, n2, acc.y);
        acc.x = fmaf(v3.x, n3, acc.x); acc.y = fmaf(v3.y, n3, acc.y);
    }
    for (; p < end; ++p) {
        int2 e0 = edges[p];
        float n0 = __builtin_bit_cast(float, e0.y);
        float2 v0 = *(const float2*)(xb + (size_t)e0.x * ss);
        acc.x = fmaf(v0.x, n0, acc.x);
        acc.y = fmaf(v0.y, n0, acc.y);
    }

    unsigned short h0, l0, h1, l1;
    split2(acc.x, h0, l0);
    split2(acc.y, h1, l1);
    unsigned hp = (unsigned)h0 | ((unsigned)h1 << 16);
    unsigned lp = (unsigned)l0 | ((unsigned)l1 << 16);
    size_t o = (size_t)node * as + coff + (size_t)lane * 2;
    *(unsigned*)(agg_hi + o) = hp;
    *(unsigned*)(agg_lo + o) = lp;
}

// ---------------- W split + transpose (W1, W2, Wd in one launch) ----------------
// W[K][256] -> [256][K] bf16 hi/lo; Wd[256][40] -> [48][256] (rows 40-47 zero).

__global__ void split_w_all(const float* __restrict__ W1, const float* __restrict__ W2,
                            const float* __restrict__ Wd,
                            unsigned short* __restrict__ w1hi, unsigned short* __restrict__ w1lo,
                            unsigned short* __restrict__ w2hi, unsigned short* __restrict__ w2lo,
                            unsigned short* __restrict__ wdhi, unsigned short* __restrict__ wdlo) {
    int i = blockIdx.x * 256 + threadIdx.x;
    if (i < 128 * 256) {
        int k = i >> 8;
        int n = i & 255;
        unsigned short h, l;
        split2(W1[i], h, l);
        w1hi[(size_t)n * 128 + k] = h;
        w1lo[(size_t)n * 128 + k] = l;
    } else if (i < 128 * 256 + 256 * 256) {
        int j = i - 128 * 256;
        int k = j >> 8;
        int n = j & 255;
        unsigned short h, l;
        split2(W2[j], h, l);
        w2hi[(size_t)n * 256 + k] = h;
        w2lo[(size_t)n * 256 + k] = l;
    } else {
        int j = i - 128 * 256 - 256 * 256;   // 0 .. 48*256-1
        int c = j >> 8;                       // 0..47
        int k = j & 255;
        float val = (c < 40) ? Wd[(size_t)k * 40 + c] : 0.0f;
        unsigned short h, l;
        split2(val, h, l);
        wdhi[(size_t)c * 256 + k] = h;
        wdlo[(size_t)c * 256 + k] = l;
    }
}

// ---------------- MFMA GEMM (split bf16, swapped operands), 128-row tile ----------------
// out[M,256] = relu(A[M,K] @ W[K,256] + b). A hi/lo bf16 [M][K], W hi/lo bf16 [256][K].
// Block: 256 thr = 4 waves; block tile 128 rows x 256 cols; wave = 128 x 64 cols.
// Per BK=32 chunk/wave: 8 L2 B-loads, then 4 HBM A-prefetch loads (B first so
// MFMA's B-wait leaves A in flight), 16 ds_reads, 96 MFMAs (~480cy) covering both
// latencies. A chunk-double-buffered in padded LDS [2][128][40] hi/lo.
// D = mfma(W_frag, A_frag): lane holds out[r=row0+rfx*16+(lane&15)]
// [c=col0+cf*16+(lane>>4)*4 + reg] -> contiguous float4 stores.

template<int K, bool RELU>
__global__ __launch_bounds__(256, 2) void gemm_mfma_kernel(
    const unsigned short* __restrict__ Ahi, const unsigned short* __restrict__ Alo,
    const unsigned short* __restrict__ Bhi, const unsigned short* __restrict__ Blo,
    const float* __restrict__ bias, float* __restrict__ out, int M)
{
    constexpr int ROWS = 128;
    __shared__ unsigned short AsH[2][ROWS][40];
    __shared__ unsigned short AsL[2][ROWS][40];

    int tid = threadIdx.x;
    int lane = tid & 63;
    int wave = tid >> 6;
    int row0 = blockIdx.x * ROWS;
    int col0 = wave * 64;
    int lr = lane & 15;
    int lhi = lane >> 4;
    int koff0 = lhi * 8;

    // staging: threads 0-127 stage hi, 128-255 stage lo; 4 short8 slots each/chunk
    const unsigned short* Asrc = (tid < 128) ? Ahi : Alo;
    int s = tid & 127;
    int srow0 = s >> 2;                     // 0..31 (slot j adds j*32)
    int skg = (s & 3) << 3;                 // 0,8,16,24

    f32x4 acc[4][8];
    #pragma unroll
    for (int i = 0; i < 4; ++i)
        #pragma unroll
        for (int j = 0; j < 8; ++j) acc[i][j] = (f32x4){0.f, 0.f, 0.f, 0.f};

    short8 rr[4];
    // prologue: stage chunk 0
    #pragma unroll
    for (int j = 0; j < 4; ++j)
        rr[j] = *(const short8*)(Asrc + (size_t)(row0 + j * 32 + srow0) * K + skg);
    #pragma unroll
    for (int j = 0; j < 4; ++j) {
        if (tid < 128) *(short8*)&AsH[0][j * 32 + srow0][skg] = rr[j];
        else           *(short8*)&AsL[0][j * 32 + srow0][skg] = rr[j];
    }
    __syncthreads();

    constexpr int NT = K / 32;
    #pragma unroll 1
    for (int t = 0; t < NT; ++t) {
        int cur = t & 1;
        int ko = t * 32 + koff0;

        // B fragments (L2-hot) — issued FIRST
        short8 bh[4], bl[4];
        #pragma unroll
        for (int cf = 0; cf < 4; ++cf) {
            size_t boff = (size_t)(col0 + cf * 16 + lr) * K + ko;
            bh[cf] = *(const short8*)(Bhi + boff);
            bl[cf] = *(const short8*)(Blo + boff);
        }

        // A prefetch for next chunk (HBM) — stays in flight during MFMA
        if (t + 1 < NT) {
            int kk = (t + 1) * 32;
            #pragma unroll
            for (int j = 0; j < 4; ++j)
                rr[j] = *(const short8*)(Asrc + (size_t)(row0 + j * 32 + srow0) * K + kk + skg);
        }

        // compute in two rf-halves to bound register pressure
        #pragma unroll
        for (int half = 0; half < 2; ++half) {
            short8 ah[4], al[4];
            #pragma unroll
            for (int rf = 0; rf < 4; ++rf) {
                int row = (half * 4 + rf) * 16 + lr;
                ah[rf] = *(const short8*)&AsH[cur][row][koff0];
                al[rf] = *(const short8*)&AsL[cur][row][koff0];
            }
            #pragma unroll
            for (int cf = 0; cf < 4; ++cf)
                #pragma unroll
                for (int rf = 0; rf < 4; ++rf) {
                    int rfx = half * 4 + rf;
                    acc[cf][rfx] = __builtin_amdgcn_mfma_f32_16x16x32_bf16(bh[cf], ah[rf], acc[cf][rfx], 0, 0, 0);
                    acc[cf][rfx] = __builtin_amdgcn_mfma_f32_16x16x32_bf16(bl[cf], ah[rf], acc[cf][rfx], 0, 0, 0);
                    acc[cf][rfx] = __builtin_amdgcn_mfma_f32_16x16x32_bf16(bh[cf], al[rf], acc[cf][rfx], 0, 0, 0);
                }
        }

        if (t + 1 < NT) {
            #pragma unroll
            for (int j = 0; j < 4; ++j) {
                if (tid < 128) *(short8*)&AsH[cur ^ 1][j * 32 + srow0][skg] = rr[j];
                else           *(short8*)&AsL[cur ^ 1][j * 32 + srow0][skg] = rr[j];
            }
        }
        __syncthreads();
    }

    // epilogue: bias + relu, float4 stores (contiguous cols per lane)
    #pragma unroll
    for (int cf = 0; cf < 4; ++cf) {
        int c = col0 + cf * 16 + lhi * 4;
        float4 bv = *(const float4*)(bias + c);
        #pragma unroll
        for (int rfx = 0; rfx < 8; ++rfx) {
            int r = row0 + rfx * 16 + lr;
            if (r < M) {
                float4 v;
                v.x = acc[cf][rfx][0] + bv.x;
                v.y = acc[cf][rfx][1] + bv.y;
                v.z = acc[cf][rfx][2] + bv.z;
                v.w = acc[cf][rfx][3] + bv.w;
                if (RELU) {
                    v.x = fmaxf(v.x, 0.f); v.y = fmaxf(v.y, 0.f);
                    v.z = fmaxf(v.z, 0.f); v.w = fmaxf(v.w, 0.f);
                }
                *(float4*)(out + (size_t)r * 256 + c) = v;
            }
        }
    }
}

// ---------------- dense head via MFMA + fused softmax (no LDS, no barriers) ----------------
// out[M,40] = softmax(h2[M,256] @ Wd[256,40] + bd). h2 read as f32, split to
// bf16 hi/lo inline (same bytes as pre-split; splitting here keeps the conv2
// GEMM's epilogue lean). Wd pre-split/transposed [48][256] (rows 40-47 zero).
// Block = 4 waves x 16 rows. Wave: 16 rows x 48 cols, acc[3] frags.
// D = mfma(Wd_frag, H_frag): lane holds row r = row0+(lane&15), cols
// c = cf*16+(lane>>4)*4+reg. Softmax per row = local max/sum + shfl_xor(16,32)
// across the 4-lane row group. float4 stores.

__global__ __launch_bounds__(256) void dense_mfma_kernel(
    const float* __restrict__ H,
    const unsigned short* __restrict__ Dhi, const unsigned short* __restrict__ Dlo,
    const float* __restrict__ bd, float* __restrict__ out, int M)
{
    int tid = threadIdx.x;
    int lane = tid & 63;
    int wave = tid >> 6;
    int row0 = blockIdx.x * 64 + wave * 16;
    int lr = lane & 15;
    int lhi = lane >> 4;
    int koff0 = lhi * 8;

    f32x4 acc[3];
    #pragma unroll
    for (int i = 0; i < 3; ++i) acc[i] = (f32x4){0.f, 0.f, 0.f, 0.f};

    size_t abase = (size_t)(row0 + lr) * 256 + koff0;

    short8 ah, al;
    {
        float4 f0 = *(const float4*)(H + abase);
        float4 f1 = *(const float4*)(H + abase + 4);
        const float* p0 = (const float*)&f0;
        const float* p1 = (const float*)&f1;
        #pragma unroll
        for (int j = 0; j < 4; ++j) {
            unsigned short h, l;
            split2(p0[j], h, l); ah[j] = (short)h; al[j] = (short)l;
            split2(p1[j], h, l); ah[4 + j] = (short)h; al[4 + j] = (short)l;
        }
    }

    #pragma unroll
    for (int t = 0; t < 8; ++t) {
        float4 f0n, f1n;
        if (t + 1 < 8) {                     // prefetch next h-chunk (f32)
            f0n = *(const float4*)(H + abase + (t + 1) * 32);
            f1n = *(const float4*)(H + abase + (t + 1) * 32 + 4);
        }
        int ko = t * 32 + koff0;
        #pragma unroll
        for (int cf = 0; cf < 3; ++cf) {
            size_t boff = (size_t)(cf * 16 + lr) * 256 + ko;
            short8 bh = *(const short8*)(Dhi + boff);
            short8 bl = *(const short8*)(Dlo + boff);
            acc[cf] = __builtin_amdgcn_mfma_f32_16x16x32_bf16(bh, ah, acc[cf], 0, 0, 0);
            acc[cf] = __builtin_amdgcn_mfma_f32_16x16x32_bf16(bl, ah, acc[cf], 0, 0, 0);
            acc[cf] = __builtin_amdgcn_mfma_f32_16x16x32_bf16(bh, al, acc[cf], 0, 0, 0);
        }
        if (t + 1 < 8) {
            const float* p0 = (const float*)&f0n;
            const float* p1 = (const float*)&f1n;
            #pragma unroll
            for (int j = 0; j < 4; ++j) {
                unsigned short h, l;
                split2(p0[j], h, l); ah[j] = (short)h; al[j] = (short)l;
                split2(p1[j], h, l); ah[4 + j] = (short)h; al[4 + j] = (short)l;
            }
        }
    }

    // logits + bias; cols c = cf*16 + lhi*4 + reg; cf==2 valid only for lhi<2
    bool v2 = (lhi < 2);
    float4 b0 = *(const float4*)(bd + lhi * 4);
    float4 b1 = *(const float4*)(bd + 16 + lhi * 4);
    float4 b2 = v2 ? *(const float4*)(bd + 32 + lhi * 4) : make_float4(0.f, 0.f, 0.f, 0.f);

    float l0[4], l1[4], l2[4];
    const float* pb0 = (const float*)&b0;
    const float* pb1 = (const float*)&b1;
    const float* pb2 = (const float*)&b2;
    #pragma unroll
    for (int j = 0; j < 4; ++j) {
        l0[j] = acc[0][j] + pb0[j];
        l1[j] = acc[1][j] + pb1[j];
        l2[j] = v2 ? (acc[2][j] + pb2[j]) : -INFINITY;
    }

    float m = l0[0];
    #pragma unroll
    for (int j = 0; j < 4; ++j) { m = fmaxf(m, l0[j]); m = fmaxf(m, l1[j]); m = fmaxf(m, l2[j]); }
    m = fmaxf(m, __shfl_xor(m, 16));
    m = fmaxf(m, __shfl_xor(m, 32));

    float e0[4], e1[4], e2[4];
    float ssum = 0.f;
    #pragma unroll
    for (int j = 0; j < 4; ++j) {
        e0[j] = expf(l0[j] - m); ssum += e0[j];
        e1[j] = expf(l1[j] - m); ssum += e1[j];
        e2[j] = v2 ? expf(l2[j] - m) : 0.f; ssum += e2[j];
    }
    ssum += __shfl_xor(ssum, 16);
    ssum += __shfl_xor(ssum, 32);

    int r = row0 + lr;
    if (r < M) {
        float is = 1.0f / ssum;
        float* orow = out + (size_t)r * 40;
        *(float4*)(orow + lhi * 4)      = make_float4(e0[0] * is, e0[1] * is, e0[2] * is, e0[3] * is);
        *(float4*)(orow + 16 + lhi * 4) = make_float4(e1[0] * is, e1[1] * is, e1[2] * is, e1[3] * is);
        if (v2)
            *(float4*)(orow + 32 + lhi * 4) = make_float4(e2[0] * is, e2[1] * is, e2[2] * is, e2[3] * is);
    }
}

// ---------------- launch ----------------

extern "C" void kernel_launch(void* const* d_in, const int* in_sizes, int n_in,
                              void* d_out, int out_size, void* d_ws, size_t ws_size,
                              hipStream_t stream) {
    const float* x  = (const float*)d_in[0];
    const int*   ei = (const int*)d_in[1];
    const float* W1 = (const float*)d_in[2];
    const float* b1 = (const float*)d_in[3];
    const float* W2 = (const float*)d_in[4];
    const float* b2 = (const float*)d_in[5];
    const float* Wd = (const float*)d_in[6];
    const float* bd = (const float*)d_in[7];
    float* out = (float*)d_out;

    const int N = N_NODES;
    const int E = in_sizes[1] / 2;
    const int* src = ei;
    const int* dst = ei + E;

    const int MP = 50048;   // M padded to multiple of 128 for MFMA tiles (128*391)

    // workspace layout (bytes, 1KB-aligned). ~110 MB.
    char* ws = (char*)d_ws;
    size_t off = 0;
    auto alloc = [&](size_t bytes) { char* p = ws + off; off += (bytes + 1023) & ~(size_t)1023; return p; };
    int*   deg    = (int*)alloc((size_t)N * 4);
    float* inv    = (float*)alloc((size_t)N * 4);
    int*   rowptr = (int*)alloc((size_t)(N + 1) * 4);
    int*   cursor = (int*)alloc((size_t)N * 4);
    int*   bsum   = (int*)alloc((size_t)64 * 4);
    int2*  edges  = (int2*)alloc((size_t)E * 8);
    float* h1     = (float*)alloc((size_t)MP * 256 * 4);                   // h1 / h2 (f32)
    unsigned short* aggU = (unsigned short*)alloc((size_t)MP * 256 * 2 * 2); // union region
    unsigned short* w1hi = (unsigned short*)alloc((size_t)128 * 256 * 2);
    unsigned short* w1lo = (unsigned short*)alloc((size_t)128 * 256 * 2);
    unsigned short* w2hi = (unsigned short*)alloc((size_t)256 * 256 * 2);
    unsigned short* w2lo = (unsigned short*)alloc((size_t)256 * 256 * 2);
    unsigned short* wdhi = (unsigned short*)alloc((size_t)48 * 256 * 2);
    unsigned short* wdlo = (unsigned short*)alloc((size_t)48 * 256 * 2);

    // union aliases: agg1 (K=128) uses first half; agg2 (K=256) uses whole region
    unsigned short* agg1_hi = aggU;
    unsigned short* agg1_lo = aggU + (size_t)MP * 128;
    unsigned short* agg2_hi = aggU;
    unsigned short* agg2_lo = aggU + (size_t)MP * 256;
    float* h2 = h1;   // conv2 gemm writes h2 into h1's buffer (h1 dead once agg2 built)

    hipMemsetAsync(deg, 0, (size_t)N * 4, stream);

    const int nb = (N + 1023) / 1024;   // 49 scan blocks

    // degree -> scan (rowptr+cursor+inv) -> bucketed packed edges
    deg_kernel<<<(E + 255) / 256, 256, 0, stream>>>(dst, deg, E);
    scan_p1<<<nb, 256, 0, stream>>>(deg, bsum, N);
    scan_p2<<<1, 64, 0, stream>>>(bsum, nb, rowptr, N);
    scan_p3<<<nb, 256, 0, stream>>>(deg, bsum, rowptr, cursor, inv, N);
    fill_kernel<<<(E + 255) / 256, 256, 0, stream>>>(src, dst, inv, cursor, edges, E);

    // pre-split weights (W1, W2, Wd transposed), one launch
    split_w_all<<<(128 * 256 + 256 * 256 + 48 * 256) / 256, 256, 0, stream>>>(
        W1, W2, Wd, w1hi, w1lo, w2hi, w2lo, wdhi, wdlo);

    const int gblocks = (N + 3) / 4;

    // conv1: gather into agg1 (split bf16), then h1 = relu(agg1 @ W1 + b1) via MFMA
    gather_agg_pass<<<gblocks, 256, 0, stream>>>(x, 0, 128, rowptr, edges, agg1_hi, agg1_lo, 128);
    gemm_mfma_kernel<128, true><<<MP / 128, 256, 0, stream>>>(
        agg1_hi, agg1_lo, w1hi, w1lo, b1, h1, N);

    // conv2: gather h1 into agg2 (two 128-col passes), then h2 = relu(...) f32
    gather_agg_pass<<<gblocks, 256, 0, stream>>>(h1, 0,   256, rowptr, edges, agg2_hi, agg2_lo, 256);
    gather_agg_pass<<<gblocks, 256, 0, stream>>>(h1, 128, 256, rowptr, edges, agg2_hi, agg2_lo, 256);
    gemm_mfma_kernel<256, true><<<MP / 128, 256, 0, stream>>>(
        agg2_hi, agg2_lo, w2hi, w2lo, b2, h2, N);

    // dense + softmax via MFMA (reads f32 h2, splits inline)
    dense_mfma_kernel<<<MP / 64, 256, 0, stream>>>(h2, wdhi, wdlo, bd, out, N);
}

// Round 17
// 297.033 us; speedup vs baseline: 1.0372x; 1.0020x over previous
//
#include <hip/hip_runtime.h>
#include <hip/hip_bf16.h>
#include <math.h>

#define N_NODES 50000

typedef short short8 __attribute__((ext_vector_type(8)));
typedef float f32x4 __attribute__((ext_vector_type(4)));

// RNE split of f32 into bf16 hi + bf16 lo (a ~= hi + lo, rel err ~2^-18)
static __device__ __forceinline__ void split2(float x, unsigned short& hi, unsigned short& lo) {
    unsigned u = __builtin_bit_cast(unsigned, x);
    unsigned r = u + 0x7FFF + ((u >> 16) & 1);
    hi = (unsigned short)(r >> 16);
    float hf = __builtin_bit_cast(float, (unsigned)hi << 16);
    float res = x - hf;
    unsigned v = __builtin_bit_cast(unsigned, res);
    unsigned r2 = v + 0x7FFF + ((v >> 16) & 1);
    lo = (unsigned short)(r2 >> 16);
}

// ---------------- degree (int histogram) ----------------

__global__ void deg_kernel(const int* __restrict__ dst, int* __restrict__ deg, int E) {
    int e = blockIdx.x * blockDim.x + threadIdx.x;
    if (e < E) atomicAdd(&deg[dst[e]], 1);
}

// ---------------- multi-block exclusive scan ----------------

__global__ void scan_p1(const int* __restrict__ deg, int* __restrict__ bsum, int n) {
    int t = threadIdx.x;                    // 256 threads
    int base = blockIdx.x * 1024 + t * 4;
    int4 v = make_int4(0, 0, 0, 0);
    if (base + 3 < n) v = *(const int4*)(deg + base);
    else {
        if (base + 0 < n) v.x = deg[base + 0];
        if (base + 1 < n) v.y = deg[base + 1];
        if (base + 2 < n) v.z = deg[base + 2];
    }
    int s = v.x + v.y + v.z + v.w;
    #pragma unroll
    for (int off = 32; off > 0; off >>= 1) s += __shfl_xor(s, off);
    __shared__ int wpart[4];
    if ((t & 63) == 0) wpart[t >> 6] = s;
    __syncthreads();
    if (t == 0) bsum[blockIdx.x] = wpart[0] + wpart[1] + wpart[2] + wpart[3];
}

__global__ void scan_p2(int* __restrict__ bsum, int nb, int* __restrict__ rowptr, int n) {
    int t = threadIdx.x;                    // 64 threads, nb <= 64
    int v = (t < nb) ? bsum[t] : 0;
    int sc = v;
    #pragma unroll
    for (int off = 1; off < 64; off <<= 1) {
        int u = __shfl_up(sc, off);
        if (t >= off) sc += u;
    }
    if (t < nb) bsum[t] = sc - v;           // exclusive block offsets
    if (t == 63) rowptr[n] = sc;            // grand total
}

// scan_p3 also computes inv_sqrt(deg) (folded kernel)
__global__ void scan_p3(const int* __restrict__ deg, const int* __restrict__ bsum,
                        int* __restrict__ rowptr, int* __restrict__ cursor,
                        float* __restrict__ inv, int n) {
    int t = threadIdx.x;                    // 256 threads
    int base = blockIdx.x * 1024 + t * 4;
    int4 v = make_int4(0, 0, 0, 0);
    if (base + 3 < n) v = *(const int4*)(deg + base);
    else {
        if (base + 0 < n) v.x = deg[base + 0];
        if (base + 1 < n) v.y = deg[base + 1];
        if (base + 2 < n) v.z = deg[base + 2];
    }
    int s = v.x + v.y + v.z + v.w;
    int lane = t & 63;
    int sc = s;
    #pragma unroll
    for (int off = 1; off < 64; off <<= 1) {
        int u = __shfl_up(sc, off);
        if (lane >= off) sc += u;
    }
    __shared__ int wpart[4], woff[4];
    if (lane == 63) wpart[t >> 6] = sc;
    __syncthreads();
    if (t == 0) { int a = 0; for (int i = 0; i < 4; ++i) { woff[i] = a; a += wpart[i]; } }
    __syncthreads();
    int run = bsum[blockIdx.x] + woff[t >> 6] + (sc - s);
    if (base + 0 < n) { rowptr[base + 0] = run; cursor[base + 0] = run; run += v.x; inv[base + 0] = rsqrtf(fmaxf((float)v.x, 1.0f)); }
    if (base + 1 < n) { rowptr[base + 1] = run; cursor[base + 1] = run; run += v.y; inv[base + 1] = rsqrtf(fmaxf((float)v.y, 1.0f)); }
    if (base + 2 < n) { rowptr[base + 2] = run; cursor[base + 2] = run; run += v.z; inv[base + 2] = rsqrtf(fmaxf((float)v.z, 1.0f)); }
    if (base + 3 < n) { rowptr[base + 3] = run; cursor[base + 3] = run; run += v.w; inv[base + 3] = rsqrtf(fmaxf((float)v.w, 1.0f)); }
}

// ---------------- bucket edges by dst (counting sort fill, packed 8B) ----------------

__global__ void fill_kernel(const int* __restrict__ src, const int* __restrict__ dst,
                            const float* __restrict__ inv, int* __restrict__ cursor,
                            int2* __restrict__ edges, int E) {
    int e = blockIdx.x * blockDim.x + threadIdx.x;
    if (e >= E) return;
    int s = src[e];
    int d = dst[e];
    int pos = atomicAdd(&cursor[d], 1);
    float nv = inv[s] * inv[d];
    edges[pos] = make_int2(s, __builtin_bit_cast(int, nv));
}

// ---------------- gather aggregation pass: one wave per node, 128 cols/pass ----------------
// edges packed as (src:int, norm:f32) int2 pairs, read sequentially per bucket.

__global__ void gather_agg_pass(const float* __restrict__ x, int coff, int ss,
                                const int* __restrict__ rowptr, const int2* __restrict__ edges,
                                unsigned short* __restrict__ agg_hi,
                                unsigned short* __restrict__ agg_lo, int as) {
    int node = blockIdx.x * 4 + (threadIdx.x >> 6);
    if (node >= N_NODES) return;
    int lane = threadIdx.x & 63;
    int beg = rowptr[node];
    int end = rowptr[node + 1];
    const float* xb = x + coff + (size_t)lane * 2;

    float2 acc = {0.0f, 0.0f};
    int p = beg;
    for (; p + 4 <= end; p += 4) {
        int2 e0 = edges[p], e1 = edges[p + 1], e2 = edges[p + 2], e3 = edges[p + 3];
        float n0 = __builtin_bit_cast(float, e0.y);
        float n1 = __builtin_bit_cast(float, e1.y);
        float n2 = __builtin_bit_cast(float, e2.y);
        float n3 = __builtin_bit_cast(float, e3.y);
        float2 v0 = *(const float2*)(xb + (size_t)e0.x * ss);
        float2 v1 = *(const float2*)(xb + (size_t)e1.x * ss);
        float2 v2 = *(const float2*)(xb + (size_t)e2.x * ss);
        float2 v3 = *(const float2*)(xb + (size_t)e3.x * ss);
        acc.x = fmaf(v0.x, n0, acc.x); acc.y = fmaf(v0.y, n0, acc.y);
        acc.x = fmaf(v1.x, n1, acc.x); acc.y = fmaf(v1.y, n1, acc.y);
        acc.x = fmaf(v2.x, n2, acc.x); acc.y = fmaf(v2.y, n2, acc.y);
        acc.x = fmaf(v3.x, n3, acc.x); acc.y = fmaf(v3.y, n3, acc.y);
    }
    for (; p < end; ++p) {
        int2 e0 = edges[p];
        float n0 = __builtin_bit_cast(float, e0.y);
        float2 v0 = *(const float2*)(xb + (size_t)e0.x * ss);
        acc.x = fmaf(v0.x, n0, acc.x);
        acc.y = fmaf(v0.y, n0, acc.y);
    }

    unsigned short h0, l0, h1, l1;
    split2(acc.x, h0, l0);
    split2(acc.y, h1, l1);
    unsigned hp = (unsigned)h0 | ((unsigned)h1 << 16);
    unsigned lp = (unsigned)l0 | ((unsigned)l1 << 16);
    size_t o = (size_t)node * as + coff + (size_t)lane * 2;
    *(unsigned*)(agg_hi + o) = hp;
    *(unsigned*)(agg_lo + o) = lp;
}

// ---------------- W split + transpose (W1, W2, Wd in one launch) ----------------
// W[K][256] -> [256][K] bf16 hi/lo; Wd[256][40] -> [48][256] (rows 40-47 zero).

__global__ void split_w_all(const float* __restrict__ W1, const float* __restrict__ W2,
                            const float* __restrict__ Wd,
                            unsigned short* __restrict__ w1hi, unsigned short* __restrict__ w1lo,
                            unsigned short* __restrict__ w2hi, unsigned short* __restrict__ w2lo,
                            unsigned short* __restrict__ wdhi, unsigned short* __restrict__ wdlo) {
    int i = blockIdx.x * 256 + threadIdx.x;
    if (i < 128 * 256) {
        int k = i >> 8;
        int n = i & 255;
        unsigned short h, l;
        split2(W1[i], h, l);
        w1hi[(size_t)n * 128 + k] = h;
        w1lo[(size_t)n * 128 + k] = l;
    } else if (i < 128 * 256 + 256 * 256) {
        int j = i - 128 * 256;
        int k = j >> 8;
        int n = j & 255;
        unsigned short h, l;
        split2(W2[j], h, l);
        w2hi[(size_t)n * 256 + k] = h;
        w2lo[(size_t)n * 256 + k] = l;
    } else {
        int j = i - 128 * 256 - 256 * 256;   // 0 .. 48*256-1
        int c = j >> 8;                       // 0..47
        int k = j & 255;
        float val = (c < 40) ? Wd[(size_t)k * 40 + c] : 0.0f;
        unsigned short h, l;
        split2(val, h, l);
        wdhi[(size_t)c * 256 + k] = h;
        wdlo[(size_t)c * 256 + k] = l;
    }
}

// ---------------- MFMA GEMM (split bf16, swapped operands), 128-row tile ----------------
// out[M,256] = relu(A[M,K] @ W[K,256] + b). A hi/lo bf16 [M][K], W hi/lo bf16 [256][K].
// Block: 256 thr = 4 waves; block tile 128 rows x 256 cols; wave = 128 x 64 cols.
// 2-DEEP A prefetch: loads for chunk t+2 issued at iter t; ds_write at iter t
// commits chunk t+1's data (issued a full iteration ~960cy earlier -> latency
// fully hidden; only chunk 0 pays full latency). LDS double-buffered
// [2][128][40] hi/lo (40KB -> 2 blocks/CU). B (L2-hot weights) loaded per chunk.
// D = mfma(W_frag, A_frag): lane holds out[r=row0+rfx*16+(lane&15)]
// [c=col0+cf*16+(lane>>4)*4 + reg] -> contiguous float4 stores.

template<int K, bool RELU>
__global__ __launch_bounds__(256, 2) void gemm_mfma_kernel(
    const unsigned short* __restrict__ Ahi, const unsigned short* __restrict__ Alo,
    const unsigned short* __restrict__ Bhi, const unsigned short* __restrict__ Blo,
    const float* __restrict__ bias, float* __restrict__ out, int M)
{
    constexpr int ROWS = 128;
    constexpr int NT = K / 32;
    __shared__ unsigned short AsH[2][ROWS][40];
    __shared__ unsigned short AsL[2][ROWS][40];

    int tid = threadIdx.x;
    int lane = tid & 63;
    int wave = tid >> 6;
    int row0 = blockIdx.x * ROWS;
    int col0 = wave * 64;
    int lr = lane & 15;
    int lhi = lane >> 4;
    int koff0 = lhi * 8;

    // staging: threads 0-127 stage hi, 128-255 stage lo; 4 short8 slots each/chunk
    const unsigned short* Asrc = (tid < 128) ? Ahi : Alo;
    int s = tid & 127;
    int srow0 = s >> 2;                     // 0..31 (slot j adds j*32)
    int skg = (s & 3) << 3;                 // 0,8,16,24

    f32x4 acc[4][8];
    #pragma unroll
    for (int i = 0; i < 4; ++i)
        #pragma unroll
        for (int j = 0; j < 8; ++j) acc[i][j] = (f32x4){0.f, 0.f, 0.f, 0.f};

    short8 rrA[4], rrB[4];
    // prologue: stage chunk 0 (one-time full-latency cost), then issue chunk 1
    #pragma unroll
    for (int j = 0; j < 4; ++j)
        rrA[j] = *(const short8*)(Asrc + (size_t)(row0 + j * 32 + srow0) * K + skg);
    #pragma unroll
    for (int j = 0; j < 4; ++j) {
        if (tid < 128) *(short8*)&AsH[0][j * 32 + srow0][skg] = rrA[j];
        else           *(short8*)&AsL[0][j * 32 + srow0][skg] = rrA[j];
    }
    if (NT > 1) {
        #pragma unroll
        for (int j = 0; j < 4; ++j)
            rrA[j] = *(const short8*)(Asrc + (size_t)(row0 + j * 32 + srow0) * K + 32 + skg);
    }
    __syncthreads();

    #pragma unroll 1
    for (int t = 0; t < NT; ++t) {
        int cur = t & 1;
        int ko = t * 32 + koff0;

        // B fragments (L2-hot) — issued FIRST
        short8 bh[4], bl[4];
        #pragma unroll
        for (int cf = 0; cf < 4; ++cf) {
            size_t boff = (size_t)(col0 + cf * 16 + lr) * K + ko;
            bh[cf] = *(const short8*)(Bhi + boff);
            bl[cf] = *(const short8*)(Blo + boff);
        }

        // issue A loads for chunk t+2 (2-deep; stays in flight across this iter)
        if (t + 2 < NT) {
            int kk = (t + 2) * 32;
            #pragma unroll
            for (int j = 0; j < 4; ++j)
                rrB[j] = *(const short8*)(Asrc + (size_t)(row0 + j * 32 + srow0) * K + kk + skg);
        }

        // compute in two rf-halves to bound register pressure
        #pragma unroll
        for (int half = 0; half < 2; ++half) {
            short8 ah[4], al[4];
            #pragma unroll
            for (int rf = 0; rf < 4; ++rf) {
                int row = (half * 4 + rf) * 16 + lr;
                ah[rf] = *(const short8*)&AsH[cur][row][koff0];
                al[rf] = *(const short8*)&AsL[cur][row][koff0];
            }
            #pragma unroll
            for (int cf = 0; cf < 4; ++cf)
                #pragma unroll
                for (int rf = 0; rf < 4; ++rf) {
                    int rfx = half * 4 + rf;
                    acc[cf][rfx] = __builtin_amdgcn_mfma_f32_16x16x32_bf16(bh[cf], ah[rf], acc[cf][rfx], 0, 0, 0);
                    acc[cf][rfx] = __builtin_amdgcn_mfma_f32_16x16x32_bf16(bl[cf], ah[rf], acc[cf][rfx], 0, 0, 0);
                    acc[cf][rfx] = __builtin_amdgcn_mfma_f32_16x16x32_bf16(bh[cf], al[rf], acc[cf][rfx], 0, 0, 0);
                }
        }

        if (t + 1 < NT) {
            // commit chunk t+1 (loaded one full iteration ago -> latency hidden)
            #pragma unroll
            for (int j = 0; j < 4; ++j) {
                if (tid < 128) *(short8*)&AsH[cur ^ 1][j * 32 + srow0][skg] = rrA[j];
                else           *(short8*)&AsL[cur ^ 1][j * 32 + srow0][skg] = rrA[j];
            }
            #pragma unroll
            for (int j = 0; j < 4; ++j) rrA[j] = rrB[j];
        }
        __syncthreads();
    }

    // epilogue: bias + relu, float4 stores (contiguous cols per lane)
    #pragma unroll
    for (int cf = 0; cf < 4; ++cf) {
        int c = col0 + cf * 16 + lhi * 4;
        float4 bv = *(const float4*)(bias + c);
        #pragma unroll
        for (int rfx = 0; rfx < 8; ++rfx) {
            int r = row0 + rfx * 16 + lr;
            if (r < M) {
                float4 v;
                v.x = acc[cf][rfx][0] + bv.x;
                v.y = acc[cf][rfx][1] + bv.y;
                v.z = acc[cf][rfx][2] + bv.z;
                v.w = acc[cf][rfx][3] + bv.w;
                if (RELU) {
                    v.x = fmaxf(v.x, 0.f); v.y = fmaxf(v.y, 0.f);
                    v.z = fmaxf(v.z, 0.f); v.w = fmaxf(v.w, 0.f);
                }
                *(float4*)(out + (size_t)r * 256 + c) = v;
            }
        }
    }
}

// ---------------- dense head via MFMA + fused softmax (no LDS, no barriers) ----------------
// out[M,40] = softmax(h2[M,256] @ Wd[256,40] + bd). h2 read as f32, split to
// bf16 hi/lo inline. Wd pre-split/transposed [48][256] (rows 40-47 zero).
// Block = 4 waves x 16 rows. Wave: 16 rows x 48 cols, acc[3] frags.
// D = mfma(Wd_frag, H_frag): lane holds row r = row0+(lane&15), cols
// c = cf*16+(lane>>4)*4+reg. Softmax per row = local max/sum + shfl_xor(16,32)
// across the 4-lane row group. float4 stores.

__global__ __launch_bounds__(256) void dense_mfma_kernel(
    const float* __restrict__ H,
    const unsigned short* __restrict__ Dhi, const unsigned short* __restrict__ Dlo,
    const float* __restrict__ bd, float* __restrict__ out, int M)
{
    int tid = threadIdx.x;
    int lane = tid & 63;
    int wave = tid >> 6;
    int row0 = blockIdx.x * 64 + wave * 16;
    int lr = lane & 15;
    int lhi = lane >> 4;
    int koff0 = lhi * 8;

    f32x4 acc[3];
    #pragma unroll
    for (int i = 0; i < 3; ++i) acc[i] = (f32x4){0.f, 0.f, 0.f, 0.f};

    size_t abase = (size_t)(row0 + lr) * 256 + koff0;

    short8 ah, al;
    {
        float4 f0 = *(const float4*)(H + abase);
        float4 f1 = *(const float4*)(H + abase + 4);
        const float* p0 = (const float*)&f0;
        const float* p1 = (const float*)&f1;
        #pragma unroll
        for (int j = 0; j < 4; ++j) {
            unsigned short h, l;
            split2(p0[j], h, l); ah[j] = (short)h; al[j] = (short)l;
            split2(p1[j], h, l); ah[4 + j] = (short)h; al[4 + j] = (short)l;
        }
    }

    #pragma unroll
    for (int t = 0; t < 8; ++t) {
        float4 f0n, f1n;
        if (t + 1 < 8) {                     // prefetch next h-chunk (f32)
            f0n = *(const float4*)(H + abase + (t + 1) * 32);
            f1n = *(const float4*)(H + abase + (t + 1) * 32 + 4);
        }
        int ko = t * 32 + koff0;
        #pragma unroll
        for (int cf = 0; cf < 3; ++cf) {
            size_t boff = (size_t)(cf * 16 + lr) * 256 + ko;
            short8 bh = *(const short8*)(Dhi + boff);
            short8 bl = *(const short8*)(Dlo + boff);
            acc[cf] = __builtin_amdgcn_mfma_f32_16x16x32_bf16(bh, ah, acc[cf], 0, 0, 0);
            acc[cf] = __builtin_amdgcn_mfma_f32_16x16x32_bf16(bl, ah, acc[cf], 0, 0, 0);
            acc[cf] = __builtin_amdgcn_mfma_f32_16x16x32_bf16(bh, al, acc[cf], 0, 0, 0);
        }
        if (t + 1 < 8) {
            const float* p0 = (const float*)&f0n;
            const float* p1 = (const float*)&f1n;
            #pragma unroll
            for (int j = 0; j < 4; ++j) {
                unsigned short h, l;
                split2(p0[j], h, l); ah[j] = (short)h; al[j] = (short)l;
                split2(p1[j], h, l); ah[4 + j] = (short)h; al[4 + j] = (short)l;
            }
        }
    }

    // logits + bias; cols c = cf*16 + lhi*4 + reg; cf==2 valid only for lhi<2
    bool v2 = (lhi < 2);
    float4 b0 = *(const float4*)(bd + lhi * 4);
    float4 b1 = *(const float4*)(bd + 16 + lhi * 4);
    float4 b2 = v2 ? *(const float4*)(bd + 32 + lhi * 4) : make_float4(0.f, 0.f, 0.f, 0.f);

    float l0[4], l1[4], l2[4];
    const float* pb0 = (const float*)&b0;
    const float* pb1 = (const float*)&b1;
    const float* pb2 = (const float*)&b2;
    #pragma unroll
    for (int j = 0; j < 4; ++j) {
        l0[j] = acc[0][j] + pb0[j];
        l1[j] = acc[1][j] + pb1[j];
        l2[j] = v2 ? (acc[2][j] + pb2[j]) : -INFINITY;
    }

    float m = l0[0];
    #pragma unroll
    for (int j = 0; j < 4; ++j) { m = fmaxf(m, l0[j]); m = fmaxf(m, l1[j]); m = fmaxf(m, l2[j]); }
    m = fmaxf(m, __shfl_xor(m, 16));
    m = fmaxf(m, __shfl_xor(m, 32));

    float e0[4], e1[4], e2[4];
    float ssum = 0.f;
    #pragma unroll
    for (int j = 0; j < 4; ++j) {
        e0[j] = expf(l0[j] - m); ssum += e0[j];
        e1[j] = expf(l1[j] - m); ssum += e1[j];
        e2[j] = v2 ? expf(l2[j] - m) : 0.f; ssum += e2[j];
    }
    ssum += __shfl_xor(ssum, 16);
    ssum += __shfl_xor(ssum, 32);

    int r = row0 + lr;
    if (r < M) {
        float is = 1.0f / ssum;
        float* orow = out + (size_t)r * 40;
        *(float4*)(orow + lhi * 4)      = make_float4(e0[0] * is, e0[1] * is, e0[2] * is, e0[3] * is);
        *(float4*)(orow + 16 + lhi * 4) = make_float4(e1[0] * is, e1[1] * is, e1[2] * is, e1[3] * is);
        if (v2)
            *(float4*)(orow + 32 + lhi * 4) = make_float4(e2[0] * is, e2[1] * is, e2[2] * is, e2[3] * is);
    }
}

// ---------------- launch ----------------

extern "C" void kernel_launch(void* const* d_in, const int* in_sizes, int n_in,
                              void* d_out, int out_size, void* d_ws, size_t ws_size,
                              hipStream_t stream) {
    const float* x  = (const float*)d_in[0];
    const int*   ei = (const int*)d_in[1];
    const float* W1 = (const float*)d_in[2];
    const float* b1 = (const float*)d_in[3];
    const float* W2 = (const float*)d_in[4];
    const float* b2 = (const float*)d_in[5];
    const float* Wd = (const float*)d_in[6];
    const float* bd = (const float*)d_in[7];
    float* out = (float*)d_out;

    const int N = N_NODES;
    const int E = in_sizes[1] / 2;
    const int* src = ei;
    const int* dst = ei + E;

    const int MP = 50048;   // M padded to multiple of 128 for MFMA tiles (128*391)

    // workspace layout (bytes, 1KB-aligned). ~110 MB.
    char* ws = (char*)d_ws;
    size_t off = 0;
    auto alloc = [&](size_t bytes) { char* p = ws + off; off += (bytes + 1023) & ~(size_t)1023; return p; };
    int*   deg    = (int*)alloc((size_t)N * 4);
    float* inv    = (float*)alloc((size_t)N * 4);
    int*   rowptr = (int*)alloc((size_t)(N + 1) * 4);
    int*   cursor = (int*)alloc((size_t)N * 4);
    int*   bsum   = (int*)alloc((size_t)64 * 4);
    int2*  edges  = (int2*)alloc((size_t)E * 8);
    float* h1     = (float*)alloc((size_t)MP * 256 * 4);                   // h1 / h2 (f32)
    unsigned short* aggU = (unsigned short*)alloc((size_t)MP * 256 * 2 * 2); // union region
    unsigned short* w1hi = (unsigned short*)alloc((size_t)128 * 256 * 2);
    unsigned short* w1lo = (unsigned short*)alloc((size_t)128 * 256 * 2);
    unsigned short* w2hi = (unsigned short*)alloc((size_t)256 * 256 * 2);
    unsigned short* w2lo = (unsigned short*)alloc((size_t)256 * 256 * 2);
    unsigned short* wdhi = (unsigned short*)alloc((size_t)48 * 256 * 2);
    unsigned short* wdlo = (unsigned short*)alloc((size_t)48 * 256 * 2);

    // union aliases: agg1 (K=128) uses first half; agg2 (K=256) uses whole region
    unsigned short* agg1_hi = aggU;
    unsigned short* agg1_lo = aggU + (size_t)MP * 128;
    unsigned short* agg2_hi = aggU;
    unsigned short* agg2_lo = aggU + (size_t)MP * 256;
    float* h2 = h1;   // conv2 gemm writes h2 into h1's buffer (h1 dead once agg2 built)

    hipMemsetAsync(deg, 0, (size_t)N * 4, stream);

    const int nb = (N + 1023) / 1024;   // 49 scan blocks

    // degree -> scan (rowptr+cursor+inv) -> bucketed packed edges
    deg_kernel<<<(E + 255) / 256, 256, 0, stream>>>(dst, deg, E);
    scan_p1<<<nb, 256, 0, stream>>>(deg, bsum, N);
    scan_p2<<<1, 64, 0, stream>>>(bsum, nb, rowptr, N);
    scan_p3<<<nb, 256, 0, stream>>>(deg, bsum, rowptr, cursor, inv, N);
    fill_kernel<<<(E + 255) / 256, 256, 0, stream>>>(src, dst, inv, cursor, edges, E);

    // pre-split weights (W1, W2, Wd transposed), one launch
    split_w_all<<<(128 * 256 + 256 * 256 + 48 * 256) / 256, 256, 0, stream>>>(
        W1, W2, Wd, w1hi, w1lo, w2hi, w2lo, wdhi, wdlo);

    const int gblocks = (N + 3) / 4;

    // conv1: gather into agg1 (split bf16), then h1 = relu(agg1 @ W1 + b1) via MFMA
    gather_agg_pass<<<gblocks, 256, 0, stream>>>(x, 0, 128, rowptr, edges, agg1_hi, agg1_lo, 128);
    gemm_mfma_kernel<128, true><<<MP / 128, 256, 0, stream>>>(
        agg1_hi, agg1_lo, w1hi, w1lo, b1, h1, N);

    // conv2: gather h1 into agg2 (two 128-col passes), then h2 = relu(...) f32
    gather_agg_pass<<<gblocks, 256, 0, stream>>>(h1, 0,   256, rowptr, edges, agg2_hi, agg2_lo, 256);
    gather_agg_pass<<<gblocks, 256, 0, stream>>>(h1, 128, 256, rowptr, edges, agg2_hi, agg2_lo, 256);
    gemm_mfma_kernel<256, true><<<MP / 128, 256, 0, stream>>>(
        agg2_hi, agg2_lo, w2hi, w2lo, b2, h2, N);

    // dense + softmax via MFMA (reads f32 h2, splits inline)
    dense_mfma_kernel<<<MP / 64, 256, 0, stream>>>(h2, wdhi, wdlo, bd, out, N);
}